// Round 1
// baseline (318.251 us; speedup 1.0000x reference)
//
#include <hip/hip_runtime.h>
#include <stdint.h>

typedef __attribute__((ext_vector_type(8))) short short8;   // 8 x bf16 (4 VGPRs)
typedef __attribute__((ext_vector_type(4))) float f32x4;
typedef __attribute__((ext_vector_type(4))) unsigned short u16x4;
typedef unsigned short bf16_t;

__device__ __forceinline__ bf16_t f2bf(float f) {
  union { float f; uint32_t u; } x; x.f = f;
  uint32_t r = x.u + 0x7fffu + ((x.u >> 16) & 1u);   // RNE
  return (bf16_t)(r >> 16);
}

// async global->LDS 16B (LDS dest = wave-uniform base + lane*16)
__device__ __forceinline__ void ld_g2l_16(const bf16_t* g, bf16_t* l) {
  __builtin_amdgcn_global_load_lds(
      (const __attribute__((address_space(1))) void*)g,
      (__attribute__((address_space(3))) void*)l, 16, 0, 0);
}

// ---------------- RoPE cos/sin tables (2048 pos x 64 freq) --------------------
__global__ void rope_tab(float* __restrict__ CS, float* __restrict__ SN) {
  int idx = blockIdx.x * 256 + threadIdx.x;   // 131072
  int i = idx & 63, pos = idx >> 6;
  float ang = (float)pos * exp2f((float)i * -0.2076205059f);  // -log2(1e4)/64
  CS[idx] = cosf(ang);
  SN[idx] = sinf(ang);
}

// ---------------- fused fp32 -> bf16 convert for all 7 tensors ----------------
__global__ void convert_all(const float* __restrict__ s0, const float* __restrict__ s1,
                            const float* __restrict__ s2, const float* __restrict__ s3,
                            const float* __restrict__ s4, const float* __restrict__ s5,
                            const float* __restrict__ s6,
                            bf16_t* __restrict__ d0, bf16_t* __restrict__ d1,
                            bf16_t* __restrict__ d2, bf16_t* __restrict__ d3,
                            bf16_t* __restrict__ d4, bf16_t* __restrict__ d5,
                            bf16_t* __restrict__ d6) {
  int i = blockIdx.x * 256 + threadIdx.x;
  const float* src; bf16_t* dst; int off;
  if (i < 5 * 1048576) {
    int t = i >> 20; off = i & 1048575;
    if (t == 0)      { src = s0; dst = d0; }
    else if (t == 1) { src = s1; dst = d1; }
    else if (t == 2) { src = s2; dst = d2; }
    else if (t == 3) { src = s3; dst = d3; }
    else             { src = s4; dst = d4; }
  } else {
    int j = i - 5 * 1048576;
    if (j < 262144) { src = s5; dst = d5; off = j; }
    else            { src = s6; dst = d6; off = j - 262144; }
  }
  f32x4 v = *(const f32x4*)(src + (size_t)off * 4);
  u16x4 o;
  o[0] = f2bf(v[0]); o[1] = f2bf(v[1]); o[2] = f2bf(v[2]); o[3] = f2bf(v[3]);
  *(u16x4*)(dst + (size_t)off * 4) = o;
}

// ---------------- NT GEMM core: C[M,N]=A[M,K]*B[N,K]^T + bias[N] --------------
template <int MODE>
__device__ __forceinline__ void gemm_core(
    bf16_t* __restrict__ As, bf16_t* __restrict__ Bs,
    const bf16_t* __restrict__ A, const bf16_t* __restrict__ Bm,
    const float* __restrict__ bias, void* __restrict__ Cout,
    int N, int K, int m0, int n0,
    const float* __restrict__ CS, const float* __restrict__ SN) {
  const int tid = threadIdx.x;
  const int lane = tid & 63, quad = lane >> 4, l16 = lane & 15;
  const int wv = tid >> 6;
  const int m_off = wv * 32;
  const int c0 = tid, c1 = tid + 256;
  const int r0 = c0 >> 2, col0 = (c0 & 3) * 8;
  const int r1 = c1 >> 2, col1 = (c1 & 3) * 8;

  f32x4 acc[2][8];
  const f32x4 zf = {0.f, 0.f, 0.f, 0.f};
#pragma unroll
  for (int mi = 0; mi < 2; ++mi)
#pragma unroll
    for (int ni = 0; ni < 8; ++ni) acc[mi][ni] = zf;

  const bf16_t* Ap0 = A + (size_t)(m0 + r0) * K + col0;
  const bf16_t* Ap1 = A + (size_t)(m0 + r1) * K + col1;
  const bf16_t* Bp0 = Bm + (size_t)(n0 + r0) * K + col0;
  const bf16_t* Bp1 = Bm + (size_t)(n0 + r1) * K + col1;
  bf16_t* lA0 = As + c0 * 8;  bf16_t* lA1 = As + c1 * 8;
  bf16_t* lB0 = Bs + c0 * 8;  bf16_t* lB1 = Bs + c1 * 8;

  for (int k0 = 0; k0 < K; k0 += 32) {
    ld_g2l_16(Ap0 + k0, lA0);
    ld_g2l_16(Ap1 + k0, lA1);
    ld_g2l_16(Bp0 + k0, lB0);
    ld_g2l_16(Bp1 + k0, lB1);
    __syncthreads();
    short8 af[2], bf[8];
#pragma unroll
    for (int mi = 0; mi < 2; ++mi)
      af[mi] = *(const short8*)(&As[(m_off + mi * 16 + l16) * 32 + quad * 8]);
#pragma unroll
    for (int ni = 0; ni < 8; ++ni)
      bf[ni] = *(const short8*)(&Bs[(ni * 16 + l16) * 32 + quad * 8]);
#pragma unroll
    for (int mi = 0; mi < 2; ++mi)
#pragma unroll
      for (int ni = 0; ni < 8; ++ni)
        acc[mi][ni] = __builtin_amdgcn_mfma_f32_16x16x32_bf16(
            af[mi], bf[ni], acc[mi][ni], 0, 0, 0);
    __syncthreads();
  }

  // C/D layout: col = lane&15 (n), row = quad*4 + reg (m)
  if (MODE == 0 || MODE == 2) {
#pragma unroll
    for (int mi = 0; mi < 2; ++mi)
#pragma unroll
      for (int ni = 0; ni < 8; ++ni) {
        int n = n0 + ni * 16 + l16;
        int mbase = m0 + m_off + mi * 16 + quad * 4;
        float bv = bias[n];
#pragma unroll
        for (int r = 0; r < 4; ++r) {
          float v = acc[mi][ni][r] + bv;
          int m = mbase + r;
          if (MODE == 0) ((float*)Cout)[(size_t)m * N + n] = v;
          else           ((bf16_t*)Cout)[(size_t)n * 2048 + m] = f2bf(v);
        }
      }
  } else {
    // RoPE via tables: i = ni*16+l16 (ni<4), partner at ni+4 (i+64). pos = m.
    const float scale = (MODE == 3) ? 0.08838834764831845f : 1.0f;
    bf16_t* dst = (bf16_t*)Cout;
#pragma unroll
    for (int mi = 0; mi < 2; ++mi)
#pragma unroll
      for (int r = 0; r < 4; ++r) {
        int m = m0 + m_off + mi * 16 + quad * 4 + r;
#pragma unroll
        for (int ni = 0; ni < 4; ++ni) {
          int i = ni * 16 + l16;
          int n_lo = n0 + i;
          float v1 = acc[mi][ni][r] + bias[n_lo];
          float v2 = acc[mi][ni + 4][r] + bias[n_lo + 64];
          float c = CS[m * 64 + i];
          float s = SN[m * 64 + i];
          float o1 = (v1 * c - v2 * s) * scale;
          float o2 = (v2 * c + v1 * s) * scale;
          dst[(size_t)m * N + n_lo] = f2bf(o1);
          dst[(size_t)m * N + n_lo + 64] = f2bf(o2);
        }
      }
  }
}

// fused Q/K/V projections: bx<16 -> Q(rope+scale), 16..19 -> K(rope), 20..23 -> V^T
__global__ __launch_bounds__(256) void gemm_qkv(
    const bf16_t* __restrict__ qb, const bf16_t* __restrict__ kb,
    const bf16_t* __restrict__ vb, const bf16_t* __restrict__ wqb,
    const bf16_t* __restrict__ wkb, const bf16_t* __restrict__ wvb,
    const float* __restrict__ bq, const float* __restrict__ bk,
    const float* __restrict__ bv, bf16_t* __restrict__ Qr,
    bf16_t* __restrict__ Kr, bf16_t* __restrict__ Vt,
    const float* __restrict__ CS, const float* __restrict__ SN) {
  __shared__ __align__(16) bf16_t As[128 * 32];
  __shared__ __align__(16) bf16_t Bs[128 * 32];
  int bx = blockIdx.x, m0 = blockIdx.y * 128;
  if (bx < 16)
    gemm_core<3>(As, Bs, qb, wqb, bq, Qr, 2048, 2048, m0, bx * 128, CS, SN);
  else if (bx < 20)
    gemm_core<4>(As, Bs, kb, wkb, bk, Kr, 512, 2048, m0, (bx - 16) * 128, CS, SN);
  else
    gemm_core<2>(As, Bs, vb, wvb, bv, Vt, 512, 2048, m0, (bx - 20) * 128, CS, SN);
}

__global__ __launch_bounds__(256) void gemm_o(
    const bf16_t* __restrict__ Ob, const bf16_t* __restrict__ wob,
    const float* __restrict__ bo, float* __restrict__ out) {
  __shared__ __align__(16) bf16_t As[128 * 32];
  __shared__ __align__(16) bf16_t Bs[128 * 32];
  gemm_core<0>(As, Bs, Ob, wob, bo, out, 2048, 2048,
               blockIdx.y * 128, blockIdx.x * 128, nullptr, nullptr);
}

// ---------------- causal GQA flash attention, split-KV + swapped QK^T ---------
// Each (h, qt) is split into 2 chunks over the KV range (flash-decoding style):
// chunk 0 = tiles [0, ceil(T/2)), chunk 1 = [ceil(T/2), T). Fixed-max softmax
// means partials combine by plain addition: O = (O0+O1)/(l0+l1). 1024 blocks,
// sizes 1..16 tiles, heavy-first -> ~4 blocks/CU (LDS 35.8 KB, lb(256,4)).
// QK^T is computed SWAPPED (mfma(K,Q)) so S lands as S[k][q] with q = lane&15:
// softmax is lane-local; the C->A-fragment transform for PV is 16 ds_bpermute
// on packed bf16 pairs (no S LDS buffer, no write->read roundtrip).
__global__ __launch_bounds__(256, 4) void attn_fwd(
    const bf16_t* __restrict__ Qr, const bf16_t* __restrict__ Kr,
    const bf16_t* __restrict__ Vt, float* __restrict__ Op0,
    float* __restrict__ Op1, float* __restrict__ Lp0,
    float* __restrict__ Lp1) {
  const int h = blockIdx.y;
  const int bx = blockIdx.x;             // 64: (qt desc) x (chunk)
  const int qt = 31 - (bx >> 1);         // heavy blocks dispatch first
  const int ch = bx & 1;
  const int T = qt + 1, sp = (T + 1) >> 1;
  const int t_beg = ch ? sp : 0;
  const int t_end = ch ? T : sp;
  float* __restrict__ Op = ch ? Op1 : Op0;
  float* __restrict__ Lp = ch ? Lp1 : Lp0;

  const int tid = threadIdx.x;
  const int wv = tid >> 6, lane = tid & 63, quad = lane >> 4, l16 = lane & 15;
  const int q_base = qt * 64 + wv * 16;
  const int hkv = h >> 2;
  const int qg = q_base + l16;           // this lane's q-row (B-operand col)

  __shared__ __align__(16) bf16_t Ks[64 * 136];   // stride 136: ~2-way max
  __shared__ __align__(16) bf16_t Vs[128 * 72];   // stride 72

  short8 qf[4];
  {
    const bf16_t* qp = Qr + (size_t)qg * 2048 + h * 128 + quad * 8;
#pragma unroll
    for (int kc = 0; kc < 4; ++kc) qf[kc] = *(const short8*)(qp + kc * 32);
  }

  const f32x4 zf = {0.f, 0.f, 0.f, 0.f};
  f32x4 o[8];
#pragma unroll
  for (int di = 0; di < 8; ++di) o[di] = zf;
  float l_acc = 0.f;

  for (int t = t_beg; t < t_end; ++t) {
    const int k0 = t * 64;
    // ---- stage K (64 rows x 128) and V^T (128 rows x 64) through VGPRs ----
#pragma unroll
    for (int j = 0; j < 4; ++j) {
      int cid = tid + j * 256;          // 1024 chunks of 16B
      int row = cid >> 4, c = cid & 15;
      f32x4 tmp = *(const f32x4*)(&Kr[(size_t)(k0 + row) * 512 + hkv * 128 + c * 8]);
      *(f32x4*)(&Ks[row * 136 + c * 8]) = tmp;
    }
#pragma unroll
    for (int j = 0; j < 4; ++j) {
      int cid = tid + j * 256;
      int row = cid >> 3, c = cid & 7;
      f32x4 tmp = *(const f32x4*)(&Vt[(size_t)(hkv * 128 + row) * 2048 + k0 + c * 8]);
      *(f32x4*)(&Vs[row * 72 + c * 8]) = tmp;
    }
    __syncthreads();

    // ---- swapped QK^T: sacc[sub][r] = S[k = sub*16+quad*4+r][q = l16] ----
    f32x4 sacc[4];
#pragma unroll
    for (int sub = 0; sub < 4; ++sub) sacc[sub] = zf;
#pragma unroll
    for (int sub = 0; sub < 4; ++sub)
#pragma unroll
      for (int kc = 0; kc < 4; ++kc) {
        short8 kf = *(const short8*)(&Ks[(sub * 16 + l16) * 136 + kc * 32 + quad * 8]);
        sacc[sub] = __builtin_amdgcn_mfma_f32_16x16x32_bf16(kf, qf[kc], sacc[sub], 0, 0, 0);
      }

    // ---- lane-local softmax (fixed max) + pack to bf16 pairs ----
    const bool diag = (k0 + 63 > q_base);
    uint32_t Dw[4][2];
#pragma unroll
    for (int sub = 0; sub < 4; ++sub) {
      float pv[4];
#pragma unroll
      for (int r = 0; r < 4; ++r) {
        float e = __expf(sacc[sub][r]);
        if (diag) {
          int kg = k0 + sub * 16 + quad * 4 + r;
          if (kg > qg) e = 0.f;
        }
        pv[r] = e;
        l_acc += e;
      }
      Dw[sub][0] = (uint32_t)f2bf(pv[0]) | ((uint32_t)f2bf(pv[1]) << 16);
      Dw[sub][1] = (uint32_t)f2bf(pv[2]) | ((uint32_t)f2bf(pv[3]) << 16);
    }

    // ---- C-layout -> A-fragment via ds_bpermute (reg crossbar, no LDS buf) --
    // target: lane(quad,l16) dword d of pf0 holds P[q=l16][k=8*quad+2d, +1];
    // source: Dw[k>>4][(k&3)>>1] at lane ((k>>2)&3)*16 + l16.
    const int aA = ((((quad * 2) & 3) << 4) + l16) << 2;       // d = 0,1
    const int aB = ((((quad * 2 + 1) & 3) << 4) + l16) << 2;   // d = 2,3
    const bool losel = quad < 2;
#define BPERM(a, x) ((uint32_t)__builtin_amdgcn_ds_bpermute((a), (int)(x)))
    union { uint32_t w[4]; short8 v; } U0, U1;
    {
      uint32_t t0, t1;
      t0 = BPERM(aA, Dw[0][0]); t1 = BPERM(aA, Dw[1][0]); U0.w[0] = losel ? t0 : t1;
      t0 = BPERM(aA, Dw[0][1]); t1 = BPERM(aA, Dw[1][1]); U0.w[1] = losel ? t0 : t1;
      t0 = BPERM(aB, Dw[0][0]); t1 = BPERM(aB, Dw[1][0]); U0.w[2] = losel ? t0 : t1;
      t0 = BPERM(aB, Dw[0][1]); t1 = BPERM(aB, Dw[1][1]); U0.w[3] = losel ? t0 : t1;
      t0 = BPERM(aA, Dw[2][0]); t1 = BPERM(aA, Dw[3][0]); U1.w[0] = losel ? t0 : t1;
      t0 = BPERM(aA, Dw[2][1]); t1 = BPERM(aA, Dw[3][1]); U1.w[1] = losel ? t0 : t1;
      t0 = BPERM(aB, Dw[2][0]); t1 = BPERM(aB, Dw[3][0]); U1.w[2] = losel ? t0 : t1;
      t0 = BPERM(aB, Dw[2][1]); t1 = BPERM(aB, Dw[3][1]); U1.w[3] = losel ? t0 : t1;
    }
#undef BPERM
    const short8 pf0 = U0.v, pf1 = U1.v;

    // ---- PV accumulate from V-LDS ----
#pragma unroll
    for (int di = 0; di < 8; ++di) {
      short8 vf0 = *(const short8*)(&Vs[(di * 16 + l16) * 72 + quad * 8]);
      short8 vf1 = *(const short8*)(&Vs[(di * 16 + l16) * 72 + 32 + quad * 8]);
      o[di] = __builtin_amdgcn_mfma_f32_16x16x32_bf16(pf0, vf0, o[di], 0, 0, 0);
      o[di] = __builtin_amdgcn_mfma_f32_16x16x32_bf16(pf1, vf1, o[di], 0, 0, 0);
    }
    __syncthreads();   // all waves done with Ks/Vs before next staging
  }

  // epilogue: write UNNORMALIZED partials (combine kernel normalizes)
  float lf = l_acc;
  lf += __shfl_xor(lf, 16);
  lf += __shfl_xor(lf, 32);
  if (quad == 0) Lp[(h << 11) + q_base + l16] = lf;
#pragma unroll
  for (int di = 0; di < 8; ++di)
#pragma unroll
    for (int r = 0; r < 4; ++r) {
      size_t row = q_base + quad * 4 + r;
      size_t col = h * 128 + di * 16 + l16;
      Op[row * 2048 + col] = o[di][r];
    }
}

// ---------------- combine split-KV partials: Ob = (O0+O1)/(l0+l1) -------------
__global__ __launch_bounds__(256) void attn_combine(
    const float* __restrict__ Op0, const float* __restrict__ Op1,
    const float* __restrict__ Lp0, const float* __restrict__ Lp1,
    bf16_t* __restrict__ Ob) {
  int idx = blockIdx.x * 256 + threadIdx.x;   // 524288 threads x 8 elems
  size_t base = (size_t)idx * 8;
  int row = (int)(base >> 11);
  int col = (int)(base & 2047);
  int h = col >> 7;
  float li = 1.0f / (Lp0[(h << 11) + row] + Lp1[(h << 11) + row]);
  f32x4 a0 = *(const f32x4*)(Op0 + base);
  f32x4 a1 = *(const f32x4*)(Op0 + base + 4);
  f32x4 b0 = *(const f32x4*)(Op1 + base);
  f32x4 b1 = *(const f32x4*)(Op1 + base + 4);
  u16x4 o0, o1;
#pragma unroll
  for (int j = 0; j < 4; ++j) {
    o0[j] = f2bf((a0[j] + b0[j]) * li);
    o1[j] = f2bf((a1[j] + b1[j]) * li);
  }
  *(u16x4*)(Ob + base) = o0;
  *(u16x4*)(Ob + base + 4) = o1;
}

// ---------------- launch ------------------------------------------------------
extern "C" void kernel_launch(void* const* d_in, const int* in_sizes, int n_in,
                              void* d_out, int out_size, void* d_ws, size_t ws_size,
                              hipStream_t stream) {
  (void)in_sizes; (void)n_in; (void)out_size; (void)ws_size;
  const float* query = (const float*)d_in[0];
  const float* key = (const float*)d_in[1];
  const float* value = (const float*)d_in[2];
  const float* Wq = (const float*)d_in[3];
  const float* bq = (const float*)d_in[4];
  const float* Wk = (const float*)d_in[5];
  const float* bk = (const float*)d_in[6];
  const float* Wv = (const float*)d_in[7];
  const float* bv = (const float*)d_in[8];
  const float* Wo = (const float*)d_in[9];
  const float* bo = (const float*)d_in[10];
  float* out = (float*)d_out;

  char* ws = (char*)d_ws;
  const size_t MB = 1024 * 1024;
  bf16_t* qb  = (bf16_t*)(ws + 0 * MB);    // 8 MB   (dead after gemm_qkv)
  bf16_t* kb  = (bf16_t*)(ws + 8 * MB);    // 8 MB   (dead after gemm_qkv)
  bf16_t* vb  = (bf16_t*)(ws + 16 * MB);   // 8 MB   (dead after gemm_qkv)
  bf16_t* wqb = (bf16_t*)(ws + 24 * MB);   // 8 MB   (dead after gemm_qkv)
  bf16_t* wkb = (bf16_t*)(ws + 32 * MB);   // 2 MB   (dead after gemm_qkv)
  bf16_t* wvb = (bf16_t*)(ws + 34 * MB);   // 2 MB   (dead after gemm_qkv)
  bf16_t* wob = (bf16_t*)(ws + 36 * MB);   // 8 MB
  bf16_t* Qr  = (bf16_t*)(ws + 44 * MB);   // 8 MB  roped+scaled Q
  bf16_t* Kr  = (bf16_t*)(ws + 52 * MB);   // 2 MB  roped K
  bf16_t* Vt  = (bf16_t*)(ws + 54 * MB);   // 2 MB  V^T (512 x 2048)
  bf16_t* Ob  = (bf16_t*)(ws + 56 * MB);   // 8 MB  attn out (bf16)
  float*  CS  = (float*)(ws + 64 * MB);    // 512 KB rope cos table
  float*  SN  = (float*)(ws + 64 * MB + 512 * 1024);  // 512 KB rope sin

  // split-KV partials alias regions dead after gemm_qkv:
  float* Op0 = (float*)(ws + 0 * MB);      // 16 MB f32 (over qb+kb)
  float* Op1 = (float*)(ws + 16 * MB);     // 16 MB f32 (over vb+wqb)
  float* Lp0 = (float*)(ws + 32 * MB);     // 128 KB   (over wkb)
  float* Lp1 = (float*)(ws + 32 * MB + 256 * 1024);   // 128 KB

  rope_tab<<<512, 256, 0, stream>>>(CS, SN);
  convert_all<<<22528, 256, 0, stream>>>(query, key, value, Wq, Wo, Wk, Wv,
                                         qb, kb, vb, wqb, wob, wkb, wvb);
  gemm_qkv<<<dim3(24, 16), 256, 0, stream>>>(qb, kb, vb, wqb, wkb, wvb,
                                             bq, bk, bv, Qr, Kr, Vt, CS, SN);
  attn_fwd<<<dim3(64, 16), 256, 0, stream>>>(Qr, Kr, Vt, Op0, Op1, Lp0, Lp1);
  attn_combine<<<2048, 256, 0, stream>>>(Op0, Op1, Lp0, Lp1, Ob);
  gemm_o<<<dim3(16, 16), 256, 0, stream>>>(Ob, wob, bo, out);
}

// Round 2
// 289.184 us; speedup vs baseline: 1.1005x; 1.1005x over previous
//
#include <hip/hip_runtime.h>
#include <stdint.h>

typedef __attribute__((ext_vector_type(8))) short short8;   // 8 x bf16 (4 VGPRs)
typedef __attribute__((ext_vector_type(4))) float f32x4;
typedef __attribute__((ext_vector_type(4))) unsigned short u16x4;
typedef unsigned short bf16_t;

__device__ __forceinline__ bf16_t f2bf(float f) {
  union { float f; uint32_t u; } x; x.f = f;
  uint32_t r = x.u + 0x7fffu + ((x.u >> 16) & 1u);   // RNE
  return (bf16_t)(r >> 16);
}

// async global->LDS 16B (LDS dest = wave-uniform base + lane*16)
__device__ __forceinline__ void ld_g2l_16(const bf16_t* g, bf16_t* l) {
  __builtin_amdgcn_global_load_lds(
      (const __attribute__((address_space(1))) void*)g,
      (__attribute__((address_space(3))) void*)l, 16, 0, 0);
}

// ---------------- RoPE cos/sin tables (2048 pos x 64 freq) --------------------
__global__ void rope_tab(float* __restrict__ CS, float* __restrict__ SN) {
  int idx = blockIdx.x * 256 + threadIdx.x;   // 131072
  int i = idx & 63, pos = idx >> 6;
  float ang = (float)pos * exp2f((float)i * -0.2076205059f);  // -log2(1e4)/64
  CS[idx] = cosf(ang);
  SN[idx] = sinf(ang);
}

// ---------------- fused fp32 -> bf16 convert for all 7 tensors ----------------
__global__ void convert_all(const float* __restrict__ s0, const float* __restrict__ s1,
                            const float* __restrict__ s2, const float* __restrict__ s3,
                            const float* __restrict__ s4, const float* __restrict__ s5,
                            const float* __restrict__ s6,
                            bf16_t* __restrict__ d0, bf16_t* __restrict__ d1,
                            bf16_t* __restrict__ d2, bf16_t* __restrict__ d3,
                            bf16_t* __restrict__ d4, bf16_t* __restrict__ d5,
                            bf16_t* __restrict__ d6) {
  int i = blockIdx.x * 256 + threadIdx.x;
  const float* src; bf16_t* dst; int off;
  if (i < 5 * 1048576) {
    int t = i >> 20; off = i & 1048575;
    if (t == 0)      { src = s0; dst = d0; }
    else if (t == 1) { src = s1; dst = d1; }
    else if (t == 2) { src = s2; dst = d2; }
    else if (t == 3) { src = s3; dst = d3; }
    else             { src = s4; dst = d4; }
  } else {
    int j = i - 5 * 1048576;
    if (j < 262144) { src = s5; dst = d5; off = j; }
    else            { src = s6; dst = d6; off = j - 262144; }
  }
  f32x4 v = *(const f32x4*)(src + (size_t)off * 4);
  u16x4 o;
  o[0] = f2bf(v[0]); o[1] = f2bf(v[1]); o[2] = f2bf(v[2]); o[3] = f2bf(v[3]);
  *(u16x4*)(dst + (size_t)off * 4) = o;
}

// ---------------- NT GEMM core: C[M,N]=A[M,K]*B[N,K]^T + bias[N] --------------
template <int MODE>
__device__ __forceinline__ void gemm_core(
    bf16_t* __restrict__ As, bf16_t* __restrict__ Bs,
    const bf16_t* __restrict__ A, const bf16_t* __restrict__ Bm,
    const float* __restrict__ bias, void* __restrict__ Cout,
    int N, int K, int m0, int n0,
    const float* __restrict__ CS, const float* __restrict__ SN) {
  const int tid = threadIdx.x;
  const int lane = tid & 63, quad = lane >> 4, l16 = lane & 15;
  const int wv = tid >> 6;
  const int m_off = wv * 32;
  const int c0 = tid, c1 = tid + 256;
  const int r0 = c0 >> 2, col0 = (c0 & 3) * 8;
  const int r1 = c1 >> 2, col1 = (c1 & 3) * 8;

  f32x4 acc[2][8];
  const f32x4 zf = {0.f, 0.f, 0.f, 0.f};
#pragma unroll
  for (int mi = 0; mi < 2; ++mi)
#pragma unroll
    for (int ni = 0; ni < 8; ++ni) acc[mi][ni] = zf;

  const bf16_t* Ap0 = A + (size_t)(m0 + r0) * K + col0;
  const bf16_t* Ap1 = A + (size_t)(m0 + r1) * K + col1;
  const bf16_t* Bp0 = Bm + (size_t)(n0 + r0) * K + col0;
  const bf16_t* Bp1 = Bm + (size_t)(n0 + r1) * K + col1;
  bf16_t* lA0 = As + c0 * 8;  bf16_t* lA1 = As + c1 * 8;
  bf16_t* lB0 = Bs + c0 * 8;  bf16_t* lB1 = Bs + c1 * 8;

  for (int k0 = 0; k0 < K; k0 += 32) {
    ld_g2l_16(Ap0 + k0, lA0);
    ld_g2l_16(Ap1 + k0, lA1);
    ld_g2l_16(Bp0 + k0, lB0);
    ld_g2l_16(Bp1 + k0, lB1);
    __syncthreads();
    short8 af[2], bf[8];
#pragma unroll
    for (int mi = 0; mi < 2; ++mi)
      af[mi] = *(const short8*)(&As[(m_off + mi * 16 + l16) * 32 + quad * 8]);
#pragma unroll
    for (int ni = 0; ni < 8; ++ni)
      bf[ni] = *(const short8*)(&Bs[(ni * 16 + l16) * 32 + quad * 8]);
#pragma unroll
    for (int mi = 0; mi < 2; ++mi)
#pragma unroll
      for (int ni = 0; ni < 8; ++ni)
        acc[mi][ni] = __builtin_amdgcn_mfma_f32_16x16x32_bf16(
            af[mi], bf[ni], acc[mi][ni], 0, 0, 0);
    __syncthreads();
  }

  // C/D layout: col = lane&15 (n), row = quad*4 + reg (m)
  if (MODE == 0 || MODE == 2) {
#pragma unroll
    for (int mi = 0; mi < 2; ++mi)
#pragma unroll
      for (int ni = 0; ni < 8; ++ni) {
        int n = n0 + ni * 16 + l16;
        int mbase = m0 + m_off + mi * 16 + quad * 4;
        float bv = bias[n];
#pragma unroll
        for (int r = 0; r < 4; ++r) {
          float v = acc[mi][ni][r] + bv;
          int m = mbase + r;
          if (MODE == 0) ((float*)Cout)[(size_t)m * N + n] = v;
          else           ((bf16_t*)Cout)[(size_t)n * 2048 + m] = f2bf(v);
        }
      }
  } else {
    // RoPE via tables: i = ni*16+l16 (ni<4), partner at ni+4 (i+64). pos = m.
    const float scale = (MODE == 3) ? 0.08838834764831845f : 1.0f;
    bf16_t* dst = (bf16_t*)Cout;
#pragma unroll
    for (int mi = 0; mi < 2; ++mi)
#pragma unroll
      for (int r = 0; r < 4; ++r) {
        int m = m0 + m_off + mi * 16 + quad * 4 + r;
#pragma unroll
        for (int ni = 0; ni < 4; ++ni) {
          int i = ni * 16 + l16;
          int n_lo = n0 + i;
          float v1 = acc[mi][ni][r] + bias[n_lo];
          float v2 = acc[mi][ni + 4][r] + bias[n_lo + 64];
          float c = CS[m * 64 + i];
          float s = SN[m * 64 + i];
          float o1 = (v1 * c - v2 * s) * scale;
          float o2 = (v2 * c + v1 * s) * scale;
          dst[(size_t)m * N + n_lo] = f2bf(o1);
          dst[(size_t)m * N + n_lo + 64] = f2bf(o2);
        }
      }
  }
}

// fused Q/K/V projections: bx<16 -> Q(rope+scale), 16..19 -> K(rope), 20..23 -> V^T
__global__ __launch_bounds__(256) void gemm_qkv(
    const bf16_t* __restrict__ qb, const bf16_t* __restrict__ kb,
    const bf16_t* __restrict__ vb, const bf16_t* __restrict__ wqb,
    const bf16_t* __restrict__ wkb, const bf16_t* __restrict__ wvb,
    const float* __restrict__ bq, const float* __restrict__ bk,
    const float* __restrict__ bv, bf16_t* __restrict__ Qr,
    bf16_t* __restrict__ Kr, bf16_t* __restrict__ Vt,
    const float* __restrict__ CS, const float* __restrict__ SN) {
  __shared__ __align__(16) bf16_t As[128 * 32];
  __shared__ __align__(16) bf16_t Bs[128 * 32];
  int bx = blockIdx.x, m0 = blockIdx.y * 128;
  if (bx < 16)
    gemm_core<3>(As, Bs, qb, wqb, bq, Qr, 2048, 2048, m0, bx * 128, CS, SN);
  else if (bx < 20)
    gemm_core<4>(As, Bs, kb, wkb, bk, Kr, 512, 2048, m0, (bx - 16) * 128, CS, SN);
  else
    gemm_core<2>(As, Bs, vb, wvb, bv, Vt, 512, 2048, m0, (bx - 20) * 128, CS, SN);
}

__global__ __launch_bounds__(256) void gemm_o(
    const bf16_t* __restrict__ Ob, const bf16_t* __restrict__ wob,
    const float* __restrict__ bo, float* __restrict__ out) {
  __shared__ __align__(16) bf16_t As[128 * 32];
  __shared__ __align__(16) bf16_t Bs[128 * 32];
  gemm_core<0>(As, Bs, Ob, wob, bo, out, 2048, 2048,
               blockIdx.y * 128, blockIdx.x * 128, nullptr, nullptr);
}

// ---------------- causal GQA flash attention ----------------------------------
// 512 blocks (32 qt x 16 h), 4 waves x 16 q-rows. K/V tiles (64 k-positions)
// double-buffered in LDS (2 x 32 KB = 64 KB -> exactly 2 blocks/CU, all blocks
// co-resident). qt = h<8 ? 31-bx : bx pairs a heavy block with a light block on
// each CU (sum = 33 tiles) -> balanced makespan, no tail.
// Staging: global_load_lds (16B DMA, no VGPR round-trip, no ds_writes) into
// LINEAR [64][128]/[128][64] tiles; bank conflicts on the stride-256B/128B
// ds_read_b128 are killed by XOR-swizzling ((row&7)<<4 on byte addr) applied to
// the per-lane GLOBAL source address at stage time and to read addresses.
// One barrier per tile: stage(t+1, buf^1) overlaps compute(t, buf).
// Swapped QK^T (mfma(K,Q)) -> softmax lane-local; C->A-frag via ds_bpermute.
__global__ __launch_bounds__(256, 2) void attn_fwd(
    const bf16_t* __restrict__ Qr, const bf16_t* __restrict__ Kr,
    const bf16_t* __restrict__ Vt, bf16_t* __restrict__ Oo) {
  const int h = blockIdx.y;
  const int bx = blockIdx.x;
  const int qt = (h < 8) ? (31 - bx) : bx;   // complementary co-resident pairing
  const int T = qt + 1;

  const int tid = threadIdx.x;
  const int wv = tid >> 6, lane = tid & 63, quad = lane >> 4, l16 = lane & 15;
  const int q_base = qt * 64 + wv * 16;
  const int hkv = h >> 2;
  const int qg = q_base + l16;               // this lane's q-row (B-operand col)
  const int swzE = (l16 & 7) << 3;           // element-space XOR swizzle (read)

  __shared__ __align__(16) bf16_t Ks[2][64 * 128];   // linear, swizzled content
  __shared__ __align__(16) bf16_t Vs[2][128 * 64];

  short8 qf[4];
  {
    const bf16_t* qp = Qr + (size_t)qg * 2048 + h * 128 + quad * 8;
#pragma unroll
    for (int kc = 0; kc < 4; ++kc) qf[kc] = *(const short8*)(qp + kc * 32);
  }

  const f32x4 zf = {0.f, 0.f, 0.f, 0.f};
  f32x4 o[8];
#pragma unroll
  for (int di = 0; di < 8; ++di) o[di] = zf;
  float l_acc = 0.f;

  // stage tile t into buffer buf: K 64x128 (16 KB) + V^T 128x64 (16 KB).
  // per wave: 4 issues x 1 KB each for K (4 rows/issue) and V (8 rows/issue).
  // LDS dest is linear (ptr == uniform base + lane*16); the XOR swizzle is
  // applied to the GLOBAL source column so swizzled data lands linearly.
  auto STAGE = [&](int buf, int t) {
    const int k0 = t * 64;
    bf16_t* KB = &Ks[buf][0];
    bf16_t* VB = &Vs[buf][0];
#pragma unroll
    for (int m = 0; m < 4; ++m) {
      int rK = wv * 16 + m * 4 + (lane >> 4);          // K tile row (k-pos)
      const bf16_t* gK = Kr + (size_t)(k0 + rK) * 512 + hkv * 128
                         + (((lane & 15) ^ ((4 * (m & 1)) | quad)) << 3);
      ld_g2l_16(gK, KB + rK * 128 + ((lane & 15) << 3));
      int rV = wv * 32 + m * 8 + (lane >> 3);          // V tile row (d)
      const bf16_t* gV = Vt + (size_t)(hkv * 128 + rV) * 2048 + k0
                         + (((lane & 7) ^ ((lane >> 3) & 7)) << 3);
      ld_g2l_16(gV, VB + rV * 64 + ((lane & 7) << 3));
    }
  };

  STAGE(0, 0);
  __syncthreads();                // barrier drains vmcnt(0): tile 0 landed
  int buf = 0;

  for (int t = 0; t < T; ++t) {
    if (t + 1 < T) STAGE(buf ^ 1, t + 1);   // prefetch overlaps compute
    const bf16_t* KB = &Ks[buf][0];
    const bf16_t* VB = &Vs[buf][0];
    const int k0 = t * 64;

    // ---- swapped QK^T: sacc[sub][r] = S[k = sub*16+quad*4+r][q = l16] ----
    f32x4 sacc[4];
#pragma unroll
    for (int sub = 0; sub < 4; ++sub) sacc[sub] = zf;
#pragma unroll
    for (int sub = 0; sub < 4; ++sub)
#pragma unroll
      for (int kc = 0; kc < 4; ++kc) {
        short8 kf = *(const short8*)(
            &KB[(sub * 16 + l16) * 128 + ((kc * 32 + quad * 8) ^ swzE)]);
        sacc[sub] = __builtin_amdgcn_mfma_f32_16x16x32_bf16(kf, qf[kc], sacc[sub], 0, 0, 0);
      }

    // ---- lane-local softmax (fixed max) + pack to bf16 pairs ----
    const bool diag = (k0 + 63 > q_base);
    uint32_t Dw[4][2];
#pragma unroll
    for (int sub = 0; sub < 4; ++sub) {
      float pv[4];
#pragma unroll
      for (int r = 0; r < 4; ++r) {
        float e = __expf(sacc[sub][r]);
        if (diag) {
          int kg = k0 + sub * 16 + quad * 4 + r;
          if (kg > qg) e = 0.f;
        }
        pv[r] = e;
        l_acc += e;
      }
      Dw[sub][0] = (uint32_t)f2bf(pv[0]) | ((uint32_t)f2bf(pv[1]) << 16);
      Dw[sub][1] = (uint32_t)f2bf(pv[2]) | ((uint32_t)f2bf(pv[3]) << 16);
    }

    // ---- C-layout -> A-fragment via ds_bpermute (reg crossbar) ----
    const int aA = ((((quad * 2) & 3) << 4) + l16) << 2;       // d = 0,1
    const int aB = ((((quad * 2 + 1) & 3) << 4) + l16) << 2;   // d = 2,3
    const bool losel = quad < 2;
#define BPERM(a, x) ((uint32_t)__builtin_amdgcn_ds_bpermute((a), (int)(x)))
    union { uint32_t w[4]; short8 v; } U0, U1;
    {
      uint32_t t0, t1;
      t0 = BPERM(aA, Dw[0][0]); t1 = BPERM(aA, Dw[1][0]); U0.w[0] = losel ? t0 : t1;
      t0 = BPERM(aA, Dw[0][1]); t1 = BPERM(aA, Dw[1][1]); U0.w[1] = losel ? t0 : t1;
      t0 = BPERM(aB, Dw[0][0]); t1 = BPERM(aB, Dw[1][0]); U0.w[2] = losel ? t0 : t1;
      t0 = BPERM(aB, Dw[0][1]); t1 = BPERM(aB, Dw[1][1]); U0.w[3] = losel ? t0 : t1;
      t0 = BPERM(aA, Dw[2][0]); t1 = BPERM(aA, Dw[3][0]); U1.w[0] = losel ? t0 : t1;
      t0 = BPERM(aA, Dw[2][1]); t1 = BPERM(aA, Dw[3][1]); U1.w[1] = losel ? t0 : t1;
      t0 = BPERM(aB, Dw[2][0]); t1 = BPERM(aB, Dw[3][0]); U1.w[2] = losel ? t0 : t1;
      t0 = BPERM(aB, Dw[2][1]); t1 = BPERM(aB, Dw[3][1]); U1.w[3] = losel ? t0 : t1;
    }
#undef BPERM
    const short8 pf0 = U0.v, pf1 = U1.v;

    // ---- PV accumulate from V-LDS (swizzled reads) ----
#pragma unroll
    for (int di = 0; di < 8; ++di) {
      short8 vf0 = *(const short8*)(
          &VB[(di * 16 + l16) * 64 + ((quad * 8) ^ swzE)]);
      short8 vf1 = *(const short8*)(
          &VB[(di * 16 + l16) * 64 + ((quad * 8 + 32) ^ swzE)]);
      o[di] = __builtin_amdgcn_mfma_f32_16x16x32_bf16(pf0, vf0, o[di], 0, 0, 0);
      o[di] = __builtin_amdgcn_mfma_f32_16x16x32_bf16(pf1, vf1, o[di], 0, 0, 0);
    }

    __asm__ volatile("s_waitcnt vmcnt(0)" ::: "memory");  // next tile landed
    __syncthreads();   // one barrier/tile: readers done + prefetch visible
    buf ^= 1;
  }

  // epilogue: reduce l across quads, normalize, write bf16
  float lf = l_acc;
  lf += __shfl_xor(lf, 16);
  lf += __shfl_xor(lf, 32);
  float linv[4];
#pragma unroll
  for (int r = 0; r < 4; ++r) linv[r] = 1.0f / __shfl(lf, quad * 4 + r, 64);
#pragma unroll
  for (int di = 0; di < 8; ++di)
#pragma unroll
    for (int r = 0; r < 4; ++r) {
      size_t row = q_base + quad * 4 + r;
      size_t col = h * 128 + di * 16 + l16;
      Oo[row * 2048 + col] = f2bf(o[di][r] * linv[r]);
    }
}

// ---------------- launch ------------------------------------------------------
extern "C" void kernel_launch(void* const* d_in, const int* in_sizes, int n_in,
                              void* d_out, int out_size, void* d_ws, size_t ws_size,
                              hipStream_t stream) {
  (void)in_sizes; (void)n_in; (void)out_size; (void)ws_size;
  const float* query = (const float*)d_in[0];
  const float* key = (const float*)d_in[1];
  const float* value = (const float*)d_in[2];
  const float* Wq = (const float*)d_in[3];
  const float* bq = (const float*)d_in[4];
  const float* Wk = (const float*)d_in[5];
  const float* bk = (const float*)d_in[6];
  const float* Wv = (const float*)d_in[7];
  const float* bv = (const float*)d_in[8];
  const float* Wo = (const float*)d_in[9];
  const float* bo = (const float*)d_in[10];
  float* out = (float*)d_out;

  char* ws = (char*)d_ws;
  const size_t MB = 1024 * 1024;
  bf16_t* qb  = (bf16_t*)(ws + 0 * MB);    // 8 MB
  bf16_t* kb  = (bf16_t*)(ws + 8 * MB);    // 8 MB
  bf16_t* vb  = (bf16_t*)(ws + 16 * MB);   // 8 MB
  bf16_t* wqb = (bf16_t*)(ws + 24 * MB);   // 8 MB
  bf16_t* wkb = (bf16_t*)(ws + 32 * MB);   // 2 MB
  bf16_t* wvb = (bf16_t*)(ws + 34 * MB);   // 2 MB
  bf16_t* wob = (bf16_t*)(ws + 36 * MB);   // 8 MB
  bf16_t* Qr  = (bf16_t*)(ws + 44 * MB);   // 8 MB  roped+scaled Q
  bf16_t* Kr  = (bf16_t*)(ws + 52 * MB);   // 2 MB  roped K
  bf16_t* Vt  = (bf16_t*)(ws + 54 * MB);   // 2 MB  V^T (512 x 2048)
  bf16_t* Ob  = (bf16_t*)(ws + 56 * MB);   // 8 MB  attn out (bf16)
  float*  CS  = (float*)(ws + 64 * MB);    // 512 KB rope cos table
  float*  SN  = (float*)(ws + 64 * MB + 512 * 1024);  // 512 KB rope sin

  rope_tab<<<512, 256, 0, stream>>>(CS, SN);
  convert_all<<<22528, 256, 0, stream>>>(query, key, value, Wq, Wo, Wk, Wv,
                                         qb, kb, vb, wqb, wob, wkb, wvb);
  gemm_qkv<<<dim3(24, 16), 256, 0, stream>>>(qb, kb, vb, wqb, wkb, wvb,
                                             bq, bk, bv, Qr, Kr, Vt, CS, SN);
  attn_fwd<<<dim3(32, 16), 256, 0, stream>>>(Qr, Kr, Vt, Ob);
  gemm_o<<<dim3(16, 16), 256, 0, stream>>>(Ob, wob, bo, out);
}

// Round 3
// 286.902 us; speedup vs baseline: 1.1093x; 1.0080x over previous
//
#include <hip/hip_runtime.h>
#include <stdint.h>

typedef __attribute__((ext_vector_type(8))) short short8;   // 8 x bf16 (4 VGPRs)
typedef __attribute__((ext_vector_type(4))) float f32x4;
typedef __attribute__((ext_vector_type(4))) unsigned short u16x4;
typedef unsigned short bf16_t;

__device__ __forceinline__ bf16_t f2bf(float f) {
  union { float f; uint32_t u; } x; x.f = f;
  uint32_t r = x.u + 0x7fffu + ((x.u >> 16) & 1u);   // RNE
  return (bf16_t)(r >> 16);
}

// async global->LDS 16B (LDS dest = wave-uniform base + lane*16)
__device__ __forceinline__ void ld_g2l_16(const bf16_t* g, bf16_t* l) {
  __builtin_amdgcn_global_load_lds(
      (const __attribute__((address_space(1))) void*)g,
      (__attribute__((address_space(3))) void*)l, 16, 0, 0);
}

// ---------------- RoPE cos/sin tables (2048 pos x 64 freq) --------------------
__global__ void rope_tab(float* __restrict__ CS, float* __restrict__ SN) {
  int idx = blockIdx.x * 256 + threadIdx.x;   // 131072
  int i = idx & 63, pos = idx >> 6;
  float ang = (float)pos * exp2f((float)i * -0.2076205059f);  // -log2(1e4)/64
  CS[idx] = cosf(ang);
  SN[idx] = sinf(ang);
}

// ---------------- fused fp32 -> bf16 convert for all 7 tensors ----------------
__global__ void convert_all(const float* __restrict__ s0, const float* __restrict__ s1,
                            const float* __restrict__ s2, const float* __restrict__ s3,
                            const float* __restrict__ s4, const float* __restrict__ s5,
                            const float* __restrict__ s6,
                            bf16_t* __restrict__ d0, bf16_t* __restrict__ d1,
                            bf16_t* __restrict__ d2, bf16_t* __restrict__ d3,
                            bf16_t* __restrict__ d4, bf16_t* __restrict__ d5,
                            bf16_t* __restrict__ d6) {
  int i = blockIdx.x * 256 + threadIdx.x;
  const float* src; bf16_t* dst; int off;
  if (i < 5 * 1048576) {
    int t = i >> 20; off = i & 1048575;
    if (t == 0)      { src = s0; dst = d0; }
    else if (t == 1) { src = s1; dst = d1; }
    else if (t == 2) { src = s2; dst = d2; }
    else if (t == 3) { src = s3; dst = d3; }
    else             { src = s4; dst = d4; }
  } else {
    int j = i - 5 * 1048576;
    if (j < 262144) { src = s5; dst = d5; off = j; }
    else            { src = s6; dst = d6; off = j - 262144; }
  }
  f32x4 v = *(const f32x4*)(src + (size_t)off * 4);
  u16x4 o;
  o[0] = f2bf(v[0]); o[1] = f2bf(v[1]); o[2] = f2bf(v[2]); o[3] = f2bf(v[3]);
  *(u16x4*)(dst + (size_t)off * 4) = o;
}

// ---------------- NT GEMM core: C[M,N]=A[M,K]*B[N,K]^T + bias[N] --------------
template <int MODE>
__device__ __forceinline__ void gemm_core(
    bf16_t* __restrict__ As, bf16_t* __restrict__ Bs,
    const bf16_t* __restrict__ A, const bf16_t* __restrict__ Bm,
    const float* __restrict__ bias, void* __restrict__ Cout,
    int N, int K, int m0, int n0,
    const float* __restrict__ CS, const float* __restrict__ SN) {
  const int tid = threadIdx.x;
  const int lane = tid & 63, quad = lane >> 4, l16 = lane & 15;
  const int wv = tid >> 6;
  const int m_off = wv * 32;
  const int c0 = tid, c1 = tid + 256;
  const int r0 = c0 >> 2, col0 = (c0 & 3) * 8;
  const int r1 = c1 >> 2, col1 = (c1 & 3) * 8;

  f32x4 acc[2][8];
  const f32x4 zf = {0.f, 0.f, 0.f, 0.f};
#pragma unroll
  for (int mi = 0; mi < 2; ++mi)
#pragma unroll
    for (int ni = 0; ni < 8; ++ni) acc[mi][ni] = zf;

  const bf16_t* Ap0 = A + (size_t)(m0 + r0) * K + col0;
  const bf16_t* Ap1 = A + (size_t)(m0 + r1) * K + col1;
  const bf16_t* Bp0 = Bm + (size_t)(n0 + r0) * K + col0;
  const bf16_t* Bp1 = Bm + (size_t)(n0 + r1) * K + col1;
  bf16_t* lA0 = As + c0 * 8;  bf16_t* lA1 = As + c1 * 8;
  bf16_t* lB0 = Bs + c0 * 8;  bf16_t* lB1 = Bs + c1 * 8;

  for (int k0 = 0; k0 < K; k0 += 32) {
    ld_g2l_16(Ap0 + k0, lA0);
    ld_g2l_16(Ap1 + k0, lA1);
    ld_g2l_16(Bp0 + k0, lB0);
    ld_g2l_16(Bp1 + k0, lB1);
    __syncthreads();
    short8 af[2], bf[8];
#pragma unroll
    for (int mi = 0; mi < 2; ++mi)
      af[mi] = *(const short8*)(&As[(m_off + mi * 16 + l16) * 32 + quad * 8]);
#pragma unroll
    for (int ni = 0; ni < 8; ++ni)
      bf[ni] = *(const short8*)(&Bs[(ni * 16 + l16) * 32 + quad * 8]);
#pragma unroll
    for (int mi = 0; mi < 2; ++mi)
#pragma unroll
      for (int ni = 0; ni < 8; ++ni)
        acc[mi][ni] = __builtin_amdgcn_mfma_f32_16x16x32_bf16(
            af[mi], bf[ni], acc[mi][ni], 0, 0, 0);
    __syncthreads();
  }

  // C/D layout: col = lane&15 (n), row = quad*4 + reg (m)
  if (MODE == 0 || MODE == 2) {
#pragma unroll
    for (int mi = 0; mi < 2; ++mi)
#pragma unroll
      for (int ni = 0; ni < 8; ++ni) {
        int n = n0 + ni * 16 + l16;
        int mbase = m0 + m_off + mi * 16 + quad * 4;
        float bv = bias[n];
#pragma unroll
        for (int r = 0; r < 4; ++r) {
          float v = acc[mi][ni][r] + bv;
          int m = mbase + r;
          if (MODE == 0) ((float*)Cout)[(size_t)m * N + n] = v;
          else           ((bf16_t*)Cout)[(size_t)n * 2048 + m] = f2bf(v);
        }
      }
  } else {
    // RoPE via tables: i = ni*16+l16 (ni<4), partner at ni+4 (i+64). pos = m.
    // MODE 3 (Q): scale = 1/sqrt(128) * log2(e)  -> attn uses exp2 directly.
    const float scale = (MODE == 3) ? 0.12751744f : 1.0f;
    bf16_t* dst = (bf16_t*)Cout;
#pragma unroll
    for (int mi = 0; mi < 2; ++mi)
#pragma unroll
      for (int r = 0; r < 4; ++r) {
        int m = m0 + m_off + mi * 16 + quad * 4 + r;
#pragma unroll
        for (int ni = 0; ni < 4; ++ni) {
          int i = ni * 16 + l16;
          int n_lo = n0 + i;
          float v1 = acc[mi][ni][r] + bias[n_lo];
          float v2 = acc[mi][ni + 4][r] + bias[n_lo + 64];
          float c = CS[m * 64 + i];
          float s = SN[m * 64 + i];
          float o1 = (v1 * c - v2 * s) * scale;
          float o2 = (v2 * c + v1 * s) * scale;
          dst[(size_t)m * N + n_lo] = f2bf(o1);
          dst[(size_t)m * N + n_lo + 64] = f2bf(o2);
        }
      }
  }
}

// fused Q/K/V projections: bx<16 -> Q(rope+scale), 16..19 -> K(rope), 20..23 -> V^T
__global__ __launch_bounds__(256) void gemm_qkv(
    const bf16_t* __restrict__ qb, const bf16_t* __restrict__ kb,
    const bf16_t* __restrict__ vb, const bf16_t* __restrict__ wqb,
    const bf16_t* __restrict__ wkb, const bf16_t* __restrict__ wvb,
    const float* __restrict__ bq, const float* __restrict__ bk,
    const float* __restrict__ bv, bf16_t* __restrict__ Qr,
    bf16_t* __restrict__ Kr, bf16_t* __restrict__ Vt,
    const float* __restrict__ CS, const float* __restrict__ SN) {
  __shared__ __align__(16) bf16_t As[128 * 32];
  __shared__ __align__(16) bf16_t Bs[128 * 32];
  int bx = blockIdx.x, m0 = blockIdx.y * 128;
  if (bx < 16)
    gemm_core<3>(As, Bs, qb, wqb, bq, Qr, 2048, 2048, m0, bx * 128, CS, SN);
  else if (bx < 20)
    gemm_core<4>(As, Bs, kb, wkb, bk, Kr, 512, 2048, m0, (bx - 16) * 128, CS, SN);
  else
    gemm_core<2>(As, Bs, vb, wvb, bv, Vt, 512, 2048, m0, (bx - 20) * 128, CS, SN);
}

__global__ __launch_bounds__(256) void gemm_o(
    const bf16_t* __restrict__ Ob, const bf16_t* __restrict__ wob,
    const float* __restrict__ bo, float* __restrict__ out) {
  __shared__ __align__(16) bf16_t As[128 * 32];
  __shared__ __align__(16) bf16_t Bs[128 * 32];
  gemm_core<0>(As, Bs, Ob, wob, bo, out, 2048, 2048,
               blockIdx.y * 128, blockIdx.x * 128, nullptr, nullptr);
}

// ---------------- causal GQA flash attention, cross-tile pipelined ------------
// Per iteration t: QK^T(t+1) (MFMA, independent) runs CONCURRENTLY with
// softmax(t) -> crossbar(t) -> PV(t) (VALU/LDS chain). K double-buffered one
// tile ahead; V at current parity; K(t+2)/V(t+1) staged at iter top.
// Buffers: K(t) in Ks[t&1], V(t) in Vs[t&1]. Region t (between barriers):
//   writes Ks[p], Vs[p^1]; reads Ks[p^1] (QK t+1), Vs[p] (PV t) -- disjoint.
// Softmax: fixed-max, exp2 (log2e folded into Q scale), v_cvt_pk_bf16_f32.
__global__ __launch_bounds__(256, 2) void attn_fwd(
    const bf16_t* __restrict__ Qr, const bf16_t* __restrict__ Kr,
    const bf16_t* __restrict__ Vt, bf16_t* __restrict__ Oo) {
  const int h = blockIdx.y;
  const int bx = blockIdx.x;
  const int qt = (h < 8) ? (31 - bx) : bx;   // complementary co-resident pairing
  const int T = qt + 1;

  const int tid = threadIdx.x;
  const int wv = tid >> 6, lane = tid & 63, quad = lane >> 4, l16 = lane & 15;
  const int q_base = qt * 64 + wv * 16;
  const int hkv = h >> 2;
  const int qg = q_base + l16;               // this lane's q-row (B-operand col)
  const int swzE = (l16 & 7) << 3;           // element-space XOR swizzle (read)

  __shared__ __align__(16) bf16_t Ks[2][64 * 128];   // linear, swizzled content
  __shared__ __align__(16) bf16_t Vs[2][128 * 64];

  short8 qf[4];
  {
    const bf16_t* qp = Qr + (size_t)qg * 2048 + h * 128 + quad * 8;
#pragma unroll
    for (int kc = 0; kc < 4; ++kc) qf[kc] = *(const short8*)(qp + kc * 32);
  }

  const f32x4 zf = {0.f, 0.f, 0.f, 0.f};
  f32x4 o[8];
#pragma unroll
  for (int di = 0; di < 8; ++di) o[di] = zf;
  float l_acc = 0.f;

  // staging (global src pre-swizzled so linear LDS dest holds swizzled tile)
  auto STAGE_K = [&](int buf, int t) {
    const int k0 = t * 64;
    bf16_t* KB = &Ks[buf][0];
#pragma unroll
    for (int m = 0; m < 4; ++m) {
      int rK = wv * 16 + m * 4 + (lane >> 4);
      const bf16_t* gK = Kr + (size_t)(k0 + rK) * 512 + hkv * 128
                         + (((lane & 15) ^ ((4 * (m & 1)) | quad)) << 3);
      ld_g2l_16(gK, KB + rK * 128 + ((lane & 15) << 3));
    }
  };
  auto STAGE_V = [&](int buf, int t) {
    const int k0 = t * 64;
    bf16_t* VB = &Vs[buf][0];
#pragma unroll
    for (int m = 0; m < 4; ++m) {
      int rV = wv * 32 + m * 8 + (lane >> 3);
      const bf16_t* gV = Vt + (size_t)(hkv * 128 + rV) * 2048 + k0
                         + (((lane & 7) ^ ((lane >> 3) & 7)) << 3);
      ld_g2l_16(gV, VB + rV * 64 + ((lane & 7) << 3));
    }
  };

  auto QK = [&](int buf, f32x4 (&s)[4]) {
    const bf16_t* KB = &Ks[buf][0];
#pragma unroll
    for (int sub = 0; sub < 4; ++sub) s[sub] = zf;
#pragma unroll
    for (int sub = 0; sub < 4; ++sub)
#pragma unroll
      for (int kc = 0; kc < 4; ++kc) {
        short8 kf = *(const short8*)(
            &KB[(sub * 16 + l16) * 128 + ((kc * 32 + quad * 8) ^ swzE)]);
        s[sub] = __builtin_amdgcn_mfma_f32_16x16x32_bf16(kf, qf[kc], s[sub], 0, 0, 0);
      }
  };

  // iteration t: stage K(t+2)/V(t+1); QK(t+1)->nxt; softmax+xbar+PV(t) from cur
  auto ITER = [&](int t, f32x4 (&cur)[4], f32x4 (&nxt)[4]) {
    const int p = t & 1;
    if (t + 2 < T) STAGE_K(p, t + 2);
    if (t + 1 < T) STAGE_V(p ^ 1, t + 1);
    if (t + 1 < T) QK(p ^ 1, nxt);

    const int k0 = t * 64;
    const bool dg = (k0 + 63 > q_base);
    uint32_t Dw[4][2];
#pragma unroll
    for (int sub = 0; sub < 4; ++sub) {
      float pv[4];
#pragma unroll
      for (int r = 0; r < 4; ++r) {
        float e = exp2f(cur[sub][r]);
        if (dg) {
          int kg = k0 + sub * 16 + quad * 4 + r;
          if (kg > qg) e = 0.f;
        }
        pv[r] = e;
        l_acc += e;
      }
      asm("v_cvt_pk_bf16_f32 %0, %1, %2" : "=v"(Dw[sub][0]) : "v"(pv[0]), "v"(pv[1]));
      asm("v_cvt_pk_bf16_f32 %0, %1, %2" : "=v"(Dw[sub][1]) : "v"(pv[2]), "v"(pv[3]));
    }

    // C-layout -> A-fragment via ds_bpermute (reg crossbar)
    const int aA = ((((quad * 2) & 3) << 4) + l16) << 2;       // d = 0,1
    const int aB = ((((quad * 2 + 1) & 3) << 4) + l16) << 2;   // d = 2,3
    const bool losel = quad < 2;
#define BPERM(a, x) ((uint32_t)__builtin_amdgcn_ds_bpermute((a), (int)(x)))
    union { uint32_t w[4]; short8 v; } U0, U1;
    {
      uint32_t t0, t1;
      t0 = BPERM(aA, Dw[0][0]); t1 = BPERM(aA, Dw[1][0]); U0.w[0] = losel ? t0 : t1;
      t0 = BPERM(aA, Dw[0][1]); t1 = BPERM(aA, Dw[1][1]); U0.w[1] = losel ? t0 : t1;
      t0 = BPERM(aB, Dw[0][0]); t1 = BPERM(aB, Dw[1][0]); U0.w[2] = losel ? t0 : t1;
      t0 = BPERM(aB, Dw[0][1]); t1 = BPERM(aB, Dw[1][1]); U0.w[3] = losel ? t0 : t1;
      t0 = BPERM(aA, Dw[2][0]); t1 = BPERM(aA, Dw[3][0]); U1.w[0] = losel ? t0 : t1;
      t0 = BPERM(aA, Dw[2][1]); t1 = BPERM(aA, Dw[3][1]); U1.w[1] = losel ? t0 : t1;
      t0 = BPERM(aB, Dw[2][0]); t1 = BPERM(aB, Dw[3][0]); U1.w[2] = losel ? t0 : t1;
      t0 = BPERM(aB, Dw[2][1]); t1 = BPERM(aB, Dw[3][1]); U1.w[3] = losel ? t0 : t1;
    }
#undef BPERM
    const short8 pf0 = U0.v, pf1 = U1.v;

    // PV accumulate from V-LDS (swizzled reads), V(t) in Vs[p]
    const bf16_t* VB = &Vs[p][0];
#pragma unroll
    for (int di = 0; di < 8; ++di) {
      short8 vf0 = *(const short8*)(
          &VB[(di * 16 + l16) * 64 + ((quad * 8) ^ swzE)]);
      short8 vf1 = *(const short8*)(
          &VB[(di * 16 + l16) * 64 + ((quad * 8 + 32) ^ swzE)]);
      o[di] = __builtin_amdgcn_mfma_f32_16x16x32_bf16(pf0, vf0, o[di], 0, 0, 0);
      o[di] = __builtin_amdgcn_mfma_f32_16x16x32_bf16(pf1, vf1, o[di], 0, 0, 0);
    }

    __asm__ volatile("s_waitcnt vmcnt(0)" ::: "memory");
    __syncthreads();
  };

  // prologue: K(0),V(0),K(1) staged; QK(0) computed before pipeline starts
  f32x4 saccA[4], saccB[4];
  STAGE_K(0, 0);
  STAGE_V(0, 0);
  if (T > 1) STAGE_K(1, 1);
  __syncthreads();              // drains staging; all waves see K0/V0/K1
  QK(0, saccA);
  __syncthreads();              // seal QK(0) reads before iter0 stages K2->Ks[0]

  int t = 0;
  for (;;) {
    ITER(t, saccA, saccB);
    if (++t >= T) break;
    ITER(t, saccB, saccA);
    if (++t >= T) break;
  }

  // epilogue: reduce l across quads, normalize, write bf16
  float lf = l_acc;
  lf += __shfl_xor(lf, 16);
  lf += __shfl_xor(lf, 32);
  float linv[4];
#pragma unroll
  for (int r = 0; r < 4; ++r) linv[r] = 1.0f / __shfl(lf, quad * 4 + r, 64);
#pragma unroll
  for (int di = 0; di < 8; ++di)
#pragma unroll
    for (int r = 0; r < 4; ++r) {
      size_t row = q_base + quad * 4 + r;
      size_t col = h * 128 + di * 16 + l16;
      Oo[row * 2048 + col] = f2bf(o[di][r] * linv[r]);
    }
}

// ---------------- launch ------------------------------------------------------
extern "C" void kernel_launch(void* const* d_in, const int* in_sizes, int n_in,
                              void* d_out, int out_size, void* d_ws, size_t ws_size,
                              hipStream_t stream) {
  (void)in_sizes; (void)n_in; (void)out_size; (void)ws_size;
  const float* query = (const float*)d_in[0];
  const float* key = (const float*)d_in[1];
  const float* value = (const float*)d_in[2];
  const float* Wq = (const float*)d_in[3];
  const float* bq = (const float*)d_in[4];
  const float* Wk = (const float*)d_in[5];
  const float* bk = (const float*)d_in[6];
  const float* Wv = (const float*)d_in[7];
  const float* bv = (const float*)d_in[8];
  const float* Wo = (const float*)d_in[9];
  const float* bo = (const float*)d_in[10];
  float* out = (float*)d_out;

  char* ws = (char*)d_ws;
  const size_t MB = 1024 * 1024;
  bf16_t* qb  = (bf16_t*)(ws + 0 * MB);    // 8 MB
  bf16_t* kb  = (bf16_t*)(ws + 8 * MB);    // 8 MB
  bf16_t* vb  = (bf16_t*)(ws + 16 * MB);   // 8 MB
  bf16_t* wqb = (bf16_t*)(ws + 24 * MB);   // 8 MB
  bf16_t* wkb = (bf16_t*)(ws + 32 * MB);   // 2 MB
  bf16_t* wvb = (bf16_t*)(ws + 34 * MB);   // 2 MB
  bf16_t* wob = (bf16_t*)(ws + 36 * MB);   // 8 MB
  bf16_t* Qr  = (bf16_t*)(ws + 44 * MB);   // 8 MB  roped+scaled Q (x log2e)
  bf16_t* Kr  = (bf16_t*)(ws + 52 * MB);   // 2 MB  roped K
  bf16_t* Vt  = (bf16_t*)(ws + 54 * MB);   // 2 MB  V^T (512 x 2048)
  bf16_t* Ob  = (bf16_t*)(ws + 56 * MB);   // 8 MB  attn out (bf16)
  float*  CS  = (float*)(ws + 64 * MB);    // 512 KB rope cos table
  float*  SN  = (float*)(ws + 64 * MB + 512 * 1024);  // 512 KB rope sin

  rope_tab<<<512, 256, 0, stream>>>(CS, SN);
  convert_all<<<22528, 256, 0, stream>>>(query, key, value, Wq, Wo, Wk, Wv,
                                         qb, kb, vb, wqb, wob, wkb, wvb);
  gemm_qkv<<<dim3(24, 16), 256, 0, stream>>>(qb, kb, vb, wqb, wkb, wvb,
                                             bq, bk, bv, Qr, Kr, Vt, CS, SN);
  attn_fwd<<<dim3(32, 16), 256, 0, stream>>>(Qr, Kr, Vt, Ob);
  gemm_o<<<dim3(16, 16), 256, 0, stream>>>(Ob, wob, bo, out);
}